// Round 4
// baseline (603.085 us; speedup 1.0000x reference)
//
#include <hip/hip_runtime.h>

#define ZP (-1.0e10f)

constexpr int TT = 2048;
constexpr int BB = 64;
constexpr int CC = 256;
constexpr int LL = 128;
constexpr int PP = 2 * LL + 1;   // 257
constexpr int HT = TT / 2;       // 1024
constexpr int SPL = 5;
constexpr int PADP = 260;
constexpr int NDEN = 512;
constexpr int NROWG = PADP / 4;  // 65
constexpr int NGATH = BB * NROWG;

__device__ __forceinline__ float lse3f(float a, float b, float c) {
  float m = fmaxf(fmaxf(a, b), c);
  float s = __expf(a - m) + __expf(b - m) + __expf(c - m);
  return m + __logf(s);
}
__device__ __forceinline__ float lse2f(float a, float b) {
  float m = fmaxf(a, b);
  return m + __logf(__expf(a - m) + __expf(b - m));
}
// log2-domain lse3: m + log2(2^(a-m)+2^(b-m)+2^(c-m)); all inputs finite.
__device__ __forceinline__ float lse3_2(float a, float b, float c) {
  float m = fmaxf(fmaxf(a, b), c);
  return m + __log2f(exp2f(a - m) + exp2f(b - m) + exp2f(c - m));
}
__device__ __forceinline__ int path_at(const int* __restrict__ tg, int p) {
  return (p & 1) ? tg[p >> 1] : 0;
}
__device__ __forceinline__ float bf2f(unsigned short u) {
  return __uint_as_float(((unsigned)u) << 16);
}
__device__ __forceinline__ unsigned short f2bf(float f) {
  unsigned u = __float_as_uint(f);
  unsigned r = (u + 0x7fffu + ((u >> 16) & 1u)) >> 16;
  return (unsigned short)r;
}

// ---- prep: gather x*log2e rows (rotated, bf16) + log-softmax denominator ---
__global__ __launch_bounds__(256) void ctc_prep(
    const float* __restrict__ x, const int* __restrict__ tgt,
    float* __restrict__ S, unsigned short* __restrict__ E) {
  const int bid = blockIdx.x;
  if (bid < NGATH) {
    const int b = bid / NROWG;
    const int p = (bid % NROWG) * 4 + (threadIdx.x >> 6);
    const int lane = threadIdx.x & 63;
    unsigned short* __restrict__ Er = E + ((size_t)(b * PADP + p)) * TT;
    if (p >= PP) {  // pad rows 257..259: log-domain "-inf" emission
      const unsigned short PB = f2bf(-1.0e9f);
      ushort4 z = {PB, PB, PB, PB};
      #pragma unroll
      for (int j = 0; j < 8; ++j) ((ushort4*)Er)[lane + j * 64] = z;
      return;
    }
    const int row = (p & 1) ? tgt[b * LL + (p >> 1)] : 0;
    const float4* __restrict__ xr = (const float4*)(x + ((size_t)b * CC + row) * TT);
    const int rot4 = (p * 17) & 511;
    const float L2E = 1.4426950408889634f;
    #pragma unroll
    for (int j = 0; j < 8; ++j) {
      const int t4 = lane + j * 64;
      float4 v = xr[t4];
      ushort4 o;
      o.x = f2bf(v.x * L2E); o.y = f2bf(v.y * L2E);
      o.z = f2bf(v.z * L2E); o.w = f2bf(v.w * L2E);
      ((ushort4*)Er)[(t4 + rot4) & 511] = o;
    }
    return;
  }
  // denominator: S[b] = sum_t lse_c x[b,c,t]
  const int d = bid - NGATH;
  const int b = d >> 3;
  const int t = ((d & 7) << 8) + threadIdx.x;
  const float* xp = x + (size_t)b * CC * TT + t;
  float m = -1e30f, s = 0.0f;
  #pragma unroll 4
  for (int c = 0; c < CC; ++c) {
    const float v = xp[(size_t)c * TT];
    const float nm = fmaxf(m, v);
    s = s * __expf(m - nm) + __expf(v - nm);
    m = nm;
  }
  float dl = m + __logf(s);
  #pragma unroll
  for (int off = 1; off < 64; off <<= 1) dl += __shfl_xor(dl, off);
  if ((threadIdx.x & 63) == 0) atomicAdd(&S[b], dl);
}

// ---- recursion: log2-domain lse3 (round-1 proven math, rotated-E layout) ---
#define LDV(dst, t4v) { _Pragma("unroll") \
  for (int j = 0; j < SPL; ++j) \
    dst[j] = *(const ushort4*)(Er[j] + ((((t4v) + rot4[j]) & 511) << 2)); }

#define FSTEPL(B, C) { \
  float u4 = __shfl_up(af[4], 1); \
  float u3 = __shfl_up(af[3], 1); \
  if (lane == 0) { u4 = ZP; u3 = ZP; } \
  float n0 = lse3_2(af[0], u4,    alw[0] ? u3    : ZP) + bf2f(B[0].C); \
  float n1 = lse3_2(af[1], af[0], alw[1] ? u4    : ZP) + bf2f(B[1].C); \
  float n2 = lse3_2(af[2], af[1], alw[2] ? af[0] : ZP) + bf2f(B[2].C); \
  float n3 = lse3_2(af[3], af[2], alw[3] ? af[1] : ZP) + bf2f(B[3].C); \
  float n4 = lse3_2(af[4], af[3], alw[4] ? af[2] : ZP) + bf2f(B[4].C); \
  af[0] = n0; af[1] = n1; af[2] = n2; af[3] = n3; af[4] = n4; }

#define BSTEPL(B, C) { \
  float d0 = __shfl_down(af[0], 1); \
  float d1 = __shfl_down(af[1], 1); \
  float n4 = lse3_2(af[4], d0,    alw[4] ? d1    : ZP) + bf2f(B[4].C); \
  float n3 = lse3_2(af[3], af[4], alw[3] ? d0    : ZP) + bf2f(B[3].C); \
  float n2 = lse3_2(af[2], af[3], alw[2] ? af[4] : ZP) + bf2f(B[2].C); \
  float n1 = lse3_2(af[1], af[2], alw[1] ? af[3] : ZP) + bf2f(B[1].C); \
  float n0 = lse3_2(af[0], af[1], alw[0] ? af[2] : ZP) + bf2f(B[0].C); \
  af[0] = n0; af[1] = n1; af[2] = n2; af[3] = n3; af[4] = n4; }

__global__ __launch_bounds__(64) void ctc_rec(
    const unsigned short* __restrict__ E, const int* __restrict__ tgt,
    float* __restrict__ wsA, float* __restrict__ wsB) {
  const int lane = threadIdx.x;
  const int b = blockIdx.x & (BB - 1);
  const bool bwd = blockIdx.x >= BB;
  const int* tg = tgt + b * LL;
  const int pbase = lane * SPL;
  const float LN2 = 0.6931471805599453f;

  const unsigned short* Er[SPL];
  int rot4[SPL];
  bool alw[SPL];
  float af[SPL];
  #pragma unroll
  for (int j = 0; j < SPL; ++j) {
    const int p = pbase + j;
    const int pc = (p < PADP) ? p : (PADP - 1);
    Er[j] = E + ((size_t)(b * PADP + pc)) * TT;
    rot4[j] = (pc * 17) & 511;
    if (!bwd) alw[j] = (p < PP) && (p >= 2) && (path_at(tg, p) != path_at(tg, p - 2));
    else      alw[j] = (p < PP) && (p + 2 < PP) && (path_at(tg, p) != path_at(tg, p + 2));
    af[j] = ZP;
    if (!bwd && p == 0) af[j] = 0.0f;
    if (bwd && p == PP - 1) af[j] = 0.0f;
  }
  ushort4 cur[SPL], nxt[SPL];

  if (!bwd) {
    LDV(cur, 0);
    for (int t4 = 0; t4 < 256; ++t4) {
      const int tn = (t4 + 1 < 256) ? t4 + 1 : 255;
      LDV(nxt, tn);
      FSTEPL(cur, x) FSTEPL(cur, y) FSTEPL(cur, z) FSTEPL(cur, w)
      #pragma unroll
      for (int j = 0; j < SPL; ++j) cur[j] = nxt[j];
    }
    #pragma unroll
    for (int j = 0; j < SPL; ++j) {
      const int p = pbase + j;
      if (p < PP) wsA[b * PADP + p] = af[j] * LN2;
    }
  } else {
    LDV(cur, 511);
    for (int t4 = 511; t4 >= 256; --t4) {
      const int tn = (t4 - 1 >= 256) ? t4 - 1 : 256;
      LDV(nxt, tn);
      BSTEPL(cur, w) BSTEPL(cur, z) BSTEPL(cur, y) BSTEPL(cur, x)
      #pragma unroll
      for (int j = 0; j < SPL; ++j) cur[j] = nxt[j];
    }
    #pragma unroll
    for (int j = 0; j < SPL; ++j) {
      const int p = pbase + j;
      if (p < PP) wsB[b * PADP + p] = af[j] * LN2;
    }
  }
}

// ---------------- fallback (round-1 proven kernel) --------------------------
__global__ __launch_bounds__(256) void ctc_main_fb(
    const float* __restrict__ x, const int* __restrict__ tgt,
    float* __restrict__ S, float* __restrict__ wsA, float* __restrict__ wsB) {
  const int bid = blockIdx.x;
  if (bid < 2 * BB) {
    if (threadIdx.x >= 64) return;
    const int lane = threadIdx.x;
    const int b = bid & (BB - 1);
    const bool bwd = (bid >= BB);
    const int* tg = tgt + b * LL;
    const float* xb = x + (size_t)b * CC * TT;
    const int pbase = lane * SPL;
    bool valid[SPL]; bool alw[SPL]; const float* rp[SPL]; float af[SPL];
    #pragma unroll
    for (int j = 0; j < SPL; ++j) {
      const int p = pbase + j;
      const bool v = (p < PP);
      valid[j] = v;
      int row = 0;
      if (v && (p & 1)) row = tg[p >> 1];
      rp[j] = xb + (size_t)row * TT;
      if (!bwd) {
        af[j] = (p == 0) ? 0.0f : ZP;
        alw[j] = (v && p >= 2) ? (path_at(tg, p) != path_at(tg, p - 2)) : false;
      } else {
        af[j] = (p == PP - 1) ? 0.0f : ZP;
        alw[j] = (v && (p + 2 < PP)) ? (path_at(tg, p) != path_at(tg, p + 2)) : false;
      }
    }
    if (!bwd) {
      float4 cur[SPL], nxt[SPL];
      #pragma unroll
      for (int j = 0; j < SPL; ++j) cur[j] = *(const float4*)(rp[j]);
      for (int tb = 0; tb < HT; tb += 4) {
        #pragma unroll
        for (int j = 0; j < SPL; ++j) nxt[j] = *(const float4*)(rp[j] + tb + 4);
        #pragma unroll
        for (int k = 0; k < 4; ++k) {
          float up4 = __shfl_up(af[4], 1);
          float up3 = __shfl_up(af[3], 1);
          if (lane == 0) { up4 = ZP; up3 = ZP; }
          const float pm1[SPL] = {up4, af[0], af[1], af[2], af[3]};
          const float pm2[SPL] = {up3, up4, af[0], af[1], af[2]};
          float na[SPL];
          #pragma unroll
          for (int j = 0; j < SPL; ++j) {
            const float em = (k == 0) ? cur[j].x : (k == 1) ? cur[j].y
                           : (k == 2) ? cur[j].z : cur[j].w;
            na[j] = lse3f(af[j], pm1[j], alw[j] ? pm2[j] : ZP) + em;
          }
          #pragma unroll
          for (int j = 0; j < SPL; ++j) af[j] = valid[j] ? na[j] : ZP;
        }
        #pragma unroll
        for (int j = 0; j < SPL; ++j) cur[j] = nxt[j];
      }
      #pragma unroll
      for (int j = 0; j < SPL; ++j)
        if (valid[j]) wsA[b * PADP + pbase + j] = af[j];
    } else {
      float4 cur[SPL], nxt[SPL];
      #pragma unroll
      for (int j = 0; j < SPL; ++j) cur[j] = *(const float4*)(rp[j] + TT - 4);
      for (int tb = TT - 4; tb >= HT; tb -= 4) {
        const int tn = (tb - 4 >= 0) ? tb - 4 : 0;
        #pragma unroll
        for (int j = 0; j < SPL; ++j) nxt[j] = *(const float4*)(rp[j] + tn);
        #pragma unroll
        for (int k = 3; k >= 0; --k) {
          float dn0 = __shfl_down(af[0], 1);
          float dn1 = __shfl_down(af[1], 1);
          const float pp1[SPL] = {af[1], af[2], af[3], af[4], dn0};
          const float pp2[SPL] = {af[2], af[3], af[4], dn0, dn1};
          float na[SPL];
          #pragma unroll
          for (int j = 0; j < SPL; ++j) {
            const float em = (k == 0) ? cur[j].x : (k == 1) ? cur[j].y
                           : (k == 2) ? cur[j].z : cur[j].w;
            na[j] = lse3f(af[j], pp1[j], alw[j] ? pp2[j] : ZP) + em;
          }
          #pragma unroll
          for (int j = 0; j < SPL; ++j) af[j] = valid[j] ? na[j] : ZP;
        }
        #pragma unroll
        for (int j = 0; j < SPL; ++j) cur[j] = nxt[j];
      }
      #pragma unroll
      for (int j = 0; j < SPL; ++j)
        if (valid[j]) wsB[b * PADP + pbase + j] = af[j];
    }
    return;
  }
  const int d = bid - 2 * BB;
  const int b = d >> 3;
  const int t = ((d & 7) << 8) + threadIdx.x;
  const float* xp = x + (size_t)b * CC * TT + t;
  float m = -1e30f, s = 0.0f;
  #pragma unroll 4
  for (int c = 0; c < CC; ++c) {
    const float v = xp[(size_t)c * TT];
    const float nm = fmaxf(m, v);
    s = s * __expf(m - nm) + __expf(v - nm);
    m = nm;
  }
  float dl = m + __logf(s);
  #pragma unroll
  for (int off = 1; off < 64; off <<= 1) dl += __shfl_xor(dl, off);
  if ((threadIdx.x & 63) == 0) atomicAdd(&S[b], dl);
}

// ---------------- final combine ---------------------------------------------
__global__ __launch_bounds__(64) void ctc_final(
    const int* __restrict__ tgt, const float* __restrict__ S,
    const float* __restrict__ wsA, const float* __restrict__ wsB,
    float* __restrict__ out) {
  const int b = blockIdx.x;
  const int lane = threadIdx.x;
  const int* tg = tgt + b * LL;
  const int pbase = lane * SPL;
  float a[SPL], bt[SPL];
  bool valid[SPL], alw[SPL];
  #pragma unroll
  for (int j = 0; j < SPL; ++j) {
    const int p = pbase + j;
    const bool v = (p < PP);
    valid[j] = v;
    a[j] = v ? wsA[b * PADP + p] : ZP;
    bt[j] = v ? wsB[b * PADP + p] : ZP;
    alw[j] = (v && (p + 2 < PP)) ? (path_at(tg, p) != path_at(tg, p + 2)) : false;
  }
  const float dn0 = __shfl_down(bt[0], 1);
  const float dn1 = __shfl_down(bt[1], 1);
  const float pp1[SPL] = {bt[1], bt[2], bt[3], bt[4], dn0};
  const float pp2[SPL] = {bt[2], bt[3], bt[4], dn0, dn1};
  float v = ZP;
  #pragma unroll
  for (int j = 0; j < SPL; ++j) {
    if (valid[j]) {
      const float comb = a[j] + lse3f(bt[j], pp1[j], alw[j] ? pp2[j] : ZP);
      v = lse2f(v, comb);
    }
  }
  #pragma unroll
  for (int off = 1; off < 64; off <<= 1) v = lse2f(v, __shfl_xor(v, off));
  if (lane == 0) out[b] = S[b] - v;
}

extern "C" void kernel_launch(void* const* d_in, const int* in_sizes, int n_in,
                              void* d_out, int out_size, void* d_ws, size_t ws_size,
                              hipStream_t stream) {
  const float* x = (const float*)d_in[0];
  const int* tgt = (const int*)d_in[1];
  float* out = (float*)d_out;

  float* S = (float*)d_ws;                     // 64 f
  float* wsA = S + 64;                         // 64*PADP f
  float* wsB = wsA + BB * PADP;                // 64*PADP f
  unsigned short* E = (unsigned short*)(wsB + BB * PADP);
  const size_t need = (size_t)(64 + 2 * BB * PADP) * 4 + (size_t)BB * PADP * TT * 2;

  hipMemsetAsync(d_ws, 0, 64 * sizeof(float), stream);
  if (ws_size >= need) {
    ctc_prep<<<dim3(NGATH + NDEN), dim3(256), 0, stream>>>(x, tgt, S, E);
    ctc_rec<<<dim3(2 * BB), dim3(64), 0, stream>>>(E, tgt, wsA, wsB);
  } else {
    ctc_main_fb<<<dim3(2 * BB + NDEN), dim3(256), 0, stream>>>(x, tgt, S, wsA, wsB);
  }
  ctc_final<<<dim3(BB), dim3(64), 0, stream>>>(tgt, S, wsA, wsB, out);
}